// Round 1
// baseline (295.910 us; speedup 1.0000x reference)
//
#include <hip/hip_runtime.h>
#include <stdint.h>

typedef unsigned short u16;
typedef __attribute__((ext_vector_type(8))) __bf16 bf16x8;
typedef __attribute__((ext_vector_type(4))) float f32x4;

#define N_IMG 64
#define C_IN  64
#define HW_IN 3136   // 56*56
#define W_IN  56
#define C_OUT 128
#define OH    54
#define OW    54
#define SPI   2916   // 54*54
#define KTOT  576    // C_IN*9
#define M_TOTAL (N_IMG*SPI)   // 186624

__device__ inline u16 f32_bf16_rne(float f) {
  unsigned u = __float_as_uint(f);
  u = (u + 0x7FFFu + ((u >> 16) & 1u)) >> 16;
  return (u16)u;
}

// wtT[co][k], k = (kh*3+kw)*64 + ci   (from OIHW: w[co][ci][kh][kw])
__global__ void convert_w(const float* __restrict__ w, u16* __restrict__ wtT) {
  int o = blockIdx.x * 256 + threadIdx.x;
  if (o >= C_OUT * KTOT) return;
  int co = o / KTOT;
  int k  = o - co * KTOT;
  int t  = k >> 6;       // kh*3+kw
  int ci = k & 63;
  wtT[o] = f32_bf16_rne(w[co * KTOT + ci * 9 + t]);
}

// xt[n][h][w][ci] (NHWC bf16) = bf16(trunc(clip(x,-128,127)))  from NCHW fp32
__global__ void convert_x(const float* __restrict__ x, u16* __restrict__ xt) {
  __shared__ u16 tile[32][34];
  int n  = blockIdx.z;
  int c0 = blockIdx.y * 32;
  int s0 = blockIdx.x * 32;
  int tx = threadIdx.x, ty = threadIdx.y;
  const float* xp = x + (size_t)n * C_IN * HW_IN;
  #pragma unroll
  for (int i = ty; i < 32; i += 8) {
    float v = xp[(c0 + i) * HW_IN + s0 + tx];
    v = fminf(fmaxf(v, -128.f), 127.f);
    int iv = (int)v;                    // trunc toward zero, matches astype(int8)
    tile[i][tx] = f32_bf16_rne((float)iv);  // exact: ints in [-128,127]
  }
  __syncthreads();
  u16* op = xt + (size_t)n * HW_IN * C_IN;
  #pragma unroll
  for (int i = ty; i < 32; i += 8) {
    op[(s0 + i) * C_IN + c0 + tx] = tile[tx][i];
  }
}

// Implicit GEMM: D[m=cout][n=spatial] += Wt[m][k] * X[k][n]
// block = 4 waves: 128 cout x 64 spatial; wave = 64 cout x 32 spatial
__global__ __launch_bounds__(256) void conv_gemm(
    const u16* __restrict__ xt, const u16* __restrict__ wtT,
    const float* __restrict__ bias, float* __restrict__ y)
{
  int tid  = threadIdx.x;
  int wv   = tid >> 6;
  int lane = tid & 63;
  int ln   = lane & 15;
  int q    = lane >> 4;

  int s_base = blockIdx.x * 64 + (wv & 1) * 32;
  int c_base = (wv >> 1) * 64;

  int img[2], oh_[2], ow_[2], pixbase[2];
  #pragma unroll
  for (int nt = 0; nt < 2; nt++) {
    int p  = s_base + nt * 16 + ln;
    int im = p / SPI;  int r  = p - im * SPI;
    int oh = r / OW;   int ow = r - oh * OW;
    img[nt] = im; oh_[nt] = oh; ow_[nt] = ow;
    pixbase[nt] = (im * HW_IN + oh * W_IN + ow) * C_IN;
  }
  int aoff[4];
  #pragma unroll
  for (int mt = 0; mt < 4; mt++)
    aoff[mt] = (c_base + mt * 16 + ln) * KTOT;

  f32x4 acc[4][2];
  #pragma unroll
  for (int mt = 0; mt < 4; mt++)
    #pragma unroll
    for (int nt = 0; nt < 2; nt++)
      acc[mt][nt] = (f32x4){0.f, 0.f, 0.f, 0.f};

  for (int kc = 0; kc < 18; kc++) {
    int kq  = (kc * 4 + q) * 8;       // first k of this lane's 8-run
    int t   = kq >> 6;                // kh*3+kw
    int ci0 = kq & 63;
    int kh  = t / 3;
    int kw  = t - kh * 3;
    int xoff = (kh * W_IN + kw) * C_IN + ci0;

    bf16x8 bf[2], af[4];
    #pragma unroll
    for (int nt = 0; nt < 2; nt++)
      bf[nt] = *(const bf16x8*)(xt + pixbase[nt] + xoff);
    #pragma unroll
    for (int mt = 0; mt < 4; mt++)
      af[mt] = *(const bf16x8*)(wtT + aoff[mt] + kq);

    #pragma unroll
    for (int mt = 0; mt < 4; mt++)
      #pragma unroll
      for (int nt = 0; nt < 2; nt++)
        acc[mt][nt] = __builtin_amdgcn_mfma_f32_16x16x32_bf16(
            af[mt], bf[nt], acc[mt][nt], 0, 0, 0);
  }

  // epilogue: D row = cout = q*4+reg, D col = spatial = ln  -> ow-coalesced stores
  #pragma unroll
  for (int nt = 0; nt < 2; nt++) {
    int obase = (img[nt] * C_OUT) * SPI + oh_[nt] * OW + ow_[nt];
    #pragma unroll
    for (int mt = 0; mt < 4; mt++) {
      int co0 = c_base + mt * 16 + q * 4;
      #pragma unroll
      for (int r = 0; r < 4; r++) {
        int co = co0 + r;
        y[obase + co * SPI] = acc[mt][nt][r] + bias[co];
      }
    }
  }
}

extern "C" void kernel_launch(void* const* d_in, const int* in_sizes, int n_in,
                              void* d_out, int out_size, void* d_ws, size_t ws_size,
                              hipStream_t stream) {
  const float* x    = (const float*)d_in[0];
  const float* w    = (const float*)d_in[1];
  const float* bias = (const float*)d_in[2];
  float* y = (float*)d_out;

  u16* wtT = (u16*)d_ws;
  u16* xt  = (u16*)((char*)d_ws + (size_t)C_OUT * KTOT * sizeof(u16)); // +147456 B

  hipLaunchKernelGGL(convert_w, dim3((C_OUT * KTOT + 255) / 256), dim3(256), 0, stream,
                     w, wtT);
  hipLaunchKernelGGL(convert_x, dim3(HW_IN / 32, C_IN / 32, N_IMG), dim3(32, 8), 0, stream,
                     x, xt);
  hipLaunchKernelGGL(conv_gemm, dim3(M_TOTAL / 64), dim3(256), 0, stream,
                     xt, wtT, bias, y);
}

// Round 2
// 187.258 us; speedup vs baseline: 1.5802x; 1.5802x over previous
//
#include <hip/hip_runtime.h>
#include <stdint.h>

typedef unsigned short u16;
typedef __attribute__((ext_vector_type(8))) __bf16 bf16x8;
typedef __attribute__((ext_vector_type(4))) float f32x4;

#define N_IMG 64
#define C_IN  64
#define HW_IN 3136   // 56*56
#define W_IN  56
#define C_OUT 128
#define OH    54
#define OW    54
#define SPI   2916   // 54*54
#define KTOT  576    // C_IN*9
#define M_TOTAL (N_IMG*SPI)   // 186624 = 128 * 1458

typedef __attribute__((address_space(3))) unsigned int lds_uint;
typedef __attribute__((address_space(1))) unsigned int gbl_uint;

__device__ __forceinline__ void load16_to_lds(const u16* g, u16* l) {
  // lane i of the wave writes LDS base + i*16 bytes; g is per-lane.
  __builtin_amdgcn_global_load_lds((const gbl_uint*)g, (lds_uint*)l, 16, 0, 0);
}

__device__ inline u16 f32_bf16_rne(float f) {
  unsigned u = __float_as_uint(f);
  u = (u + 0x7FFFu + ((u >> 16) & 1u)) >> 16;
  return (u16)u;
}

// wtT[co][k], k = (kh*3+kw)*64 + ci   (from OIHW: w[co][ci][kh][kw])
__global__ void convert_w(const float* __restrict__ w, u16* __restrict__ wtT) {
  int o = blockIdx.x * 256 + threadIdx.x;
  if (o >= C_OUT * KTOT) return;
  int co = o / KTOT;
  int k  = o - co * KTOT;
  int t  = k >> 6;       // kh*3+kw
  int ci = k & 63;
  wtT[o] = f32_bf16_rne(w[co * KTOT + ci * 9 + t]);
}

// xt[n][h][w][ci] (NHWC bf16) = bf16(trunc(clip(x,-128,127)))  from NCHW fp32
// block (64,4): 64 ci x 64 spatial tile, LDS transpose with +2 u16 pad
__global__ __launch_bounds__(256) void convert_x(const float* __restrict__ x,
                                                 u16* __restrict__ xt) {
  __shared__ u16 tile[64][66];
  int n  = blockIdx.y;
  int s0 = blockIdx.x * 64;
  int tx = threadIdx.x, ty = threadIdx.y;
  const float* xp = x + (size_t)n * C_IN * HW_IN;
  #pragma unroll
  for (int i = ty; i < 64; i += 4) {            // i = ci row; 256 B coalesced read
    float v = xp[i * HW_IN + s0 + tx];
    v = fminf(fmaxf(v, -128.f), 127.f);
    int iv = (int)v;                            // trunc toward zero = astype(int8)
    tile[i][tx] = f32_bf16_rne((float)iv);      // exact: small ints in bf16
  }
  __syncthreads();
  u16* op = xt + (size_t)n * HW_IN * C_IN;
  #pragma unroll
  for (int i = ty; i < 64; i += 4) {            // i = spatial row; 128 B coalesced write
    op[(size_t)(s0 + i) * C_IN + tx] = tile[tx][i];
  }
}

// Implicit GEMM, m97-style: block tile 128 spatial x 128 cout, BK=64 (one 3x3 tap),
// 9 chunks, 2-barrier K-loop, global_load_lds(16B) staging with XOR-16B-group swizzle.
__global__ __launch_bounds__(256) void conv_gemm(
    const u16* __restrict__ xt, const u16* __restrict__ wtT,
    const float* __restrict__ bias, float* __restrict__ y)
{
  __shared__ u16 sP[128 * 64];   // pixels  [local spatial row][swizzled 16B groups]
  __shared__ u16 sW[128 * 64];   // weights [cout row][swizzled 16B groups]

  int tid  = threadIdx.x;
  int wv   = tid >> 6;
  int lane = tid & 63;
  int ln   = lane & 15;
  int q    = lane >> 4;
  int wy   = wv >> 1;            // cout half
  int wx   = wv & 1;             // spatial half

  int blk_sp0 = blockIdx.x * 128;

  // ---- staging addresses (lane i -> row i>>3, 16B-group i&7, swizzle cg^row8) ----
  int r8 = lane >> 3;            // 0..7
  int cg = lane & 7;             // 16B group
  int scol = (cg ^ r8) * 8;      // u16 offset of swizzled group within 64

  int pix_off[4], wt_off[4];
  #pragma unroll
  for (int j = 0; j < 4; j++) {
    int srow = wv * 32 + j * 8 + r8;           // 0..127
    // pixel global base for this row (chunk adds tap offset)
    int p   = blk_sp0 + srow;
    int img = p / SPI;  int rem = p - img * SPI;
    int oh  = rem / OW; int ow  = rem - oh * OW;
    pix_off[j] = (img * HW_IN + oh * W_IN + ow) * C_IN + scol;
    wt_off[j]  = srow * KTOT + scol;
  }

  f32x4 acc[4][4];
  #pragma unroll
  for (int mt = 0; mt < 4; mt++)
    #pragma unroll
    for (int nt = 0; nt < 4; nt++)
      acc[mt][nt] = (f32x4){0.f, 0.f, 0.f, 0.f};

  // frag-read row bases (u16 index); row&7 == ln&7 for the unswizzle
  int wrow[4], prow[4];
  #pragma unroll
  for (int i = 0; i < 4; i++) {
    wrow[i] = (wy * 64 + i * 16 + ln) * 64;
    prow[i] = (wx * 64 + i * 16 + ln) * 64;
  }
  int l7 = ln & 7;

  #pragma unroll
  for (int kc = 0; kc < 9; kc++) {
    int kh = kc / 3, kw = kc - kh * 3;
    int xoff = (kh * W_IN + kw) * C_IN;

    __syncthreads();   // previous chunk's reads done before overwrite
    #pragma unroll
    for (int j = 0; j < 4; j++)
      load16_to_lds(xt + pix_off[j] + xoff, sP + (wv * 32 + j * 8) * 64);
    #pragma unroll
    for (int j = 0; j < 4; j++)
      load16_to_lds(wtT + wt_off[j] + kc * 64, sW + (wv * 32 + j * 8) * 64);
    __syncthreads();   // staging complete (compiler drains vmcnt before barrier)

    #pragma unroll
    for (int s = 0; s < 2; s++) {
      int pg = ((s * 4 + q) ^ l7) * 8;         // unswizzled physical group
      bf16x8 wf[4], pf[4];
      #pragma unroll
      for (int mt = 0; mt < 4; mt++)
        wf[mt] = *(const bf16x8*)(sW + wrow[mt] + pg);
      #pragma unroll
      for (int nt = 0; nt < 4; nt++)
        pf[nt] = *(const bf16x8*)(sP + prow[nt] + pg);
      #pragma unroll
      for (int mt = 0; mt < 4; mt++)
        #pragma unroll
        for (int nt = 0; nt < 4; nt++)
          acc[mt][nt] = __builtin_amdgcn_mfma_f32_16x16x32_bf16(
              wf[mt], pf[nt], acc[mt][nt], 0, 0, 0);
    }
  }

  // epilogue: D row = cout = q*4+reg (within 16-tile), D col = spatial = ln
  #pragma unroll
  for (int nt = 0; nt < 4; nt++) {
    int p   = blk_sp0 + wx * 64 + nt * 16 + ln;
    int img = p / SPI;  int rem = p - img * SPI;
    int oh  = rem / OW; int ow  = rem - oh * OW;
    int obase = img * C_OUT * SPI + oh * OW + ow;
    #pragma unroll
    for (int mt = 0; mt < 4; mt++) {
      int co0 = wy * 64 + mt * 16 + q * 4;
      #pragma unroll
      for (int r = 0; r < 4; r++) {
        int co = co0 + r;
        y[obase + co * SPI] = acc[mt][nt][r] + bias[co];
      }
    }
  }
}

extern "C" void kernel_launch(void* const* d_in, const int* in_sizes, int n_in,
                              void* d_out, int out_size, void* d_ws, size_t ws_size,
                              hipStream_t stream) {
  const float* x    = (const float*)d_in[0];
  const float* w    = (const float*)d_in[1];
  const float* bias = (const float*)d_in[2];
  float* y = (float*)d_out;

  u16* wtT = (u16*)d_ws;
  u16* xt  = (u16*)((char*)d_ws + (size_t)C_OUT * KTOT * sizeof(u16)); // +147456 B

  hipLaunchKernelGGL(convert_w, dim3((C_OUT * KTOT + 255) / 256), dim3(256), 0, stream,
                     w, wtT);
  hipLaunchKernelGGL(convert_x, dim3(HW_IN / 64, N_IMG), dim3(64, 4), 0, stream,
                     x, xt);
  hipLaunchKernelGGL(conv_gemm, dim3(M_TOTAL / 128), dim3(256), 0, stream,
                     xt, wtT, bias, y);
}